// Round 11
// baseline (68.355 us; speedup 1.0000x reference)
//
#include <hip/hip_runtime.h>

#define NB  16   // batch
#define NN  64   // nodes
#define NFD 64   // node features
#define EFD 5    // edge types
#define MFD 64   // message features
#define THREADS 256   // 4 waves

typedef const __attribute__((address_space(1))) void* gas_ptr;
typedef __attribute__((address_space(3))) void*       las_ptr;

// R11 = R10 with load placement fixed:
//  - all 80 W register loads hoisted ABOVE barrier #1 (one concurrent miss
//    round with the afm DMA; compiler cannot hoist loads across a barrier
//    itself, so this must be source-level)
//  - att (adj_a gather, dependent on a_bfm) moved BELOW barrier #1 so its
//    miss latency hides under phases 2+3 instead of serializing pre-barrier.
__global__ __launch_bounds__(THREADS)
void ggnn_msgpass_kernel(const float* __restrict__ afm,    // (B,N,NF)
                         const int*   __restrict__ bfm,    // (B,N,N)
                         const int*   __restrict__ a_bfm,  // (B,N)
                         const float* __restrict__ adj_w,  // (EF,MF,NF)
                         const float* __restrict__ adj_a,  // (AEF,MF)
                         const float* __restrict__ bias,   // (MF)
                         float* __restrict__ out)          // (B,N,MF)
{
    __shared__ float afm_s[NN * NFD];        // 16 KB
    __shared__ float ac_s[4][EFD][NFD];      // 5 KB: per-row bucket sums

    const int t    = threadIdx.x;
    const int lane = t & 63;
    const int g    = t >> 6;            // wave id
    const int bx   = blockIdx.x;        // 256 blocks = 16 b * 16 rowtiles
    const int b    = bx >> 4;
    const int i0   = (bx & 15) << 2;    // 4 rows per block
    const int i    = i0 + g;            // phase-2 row of this wave

    // ---- async DMA: afm[b] (16 KB, 4 issues/wave, fire-and-forget) ----
    {
        const float4* asrc = (const float4*)(afm + (size_t)b * NN * NFD);
#pragma unroll
        for (int k = 0; k < 4; ++k) {
            int q = g * 4 + k;
            __builtin_amdgcn_global_load_lds((gas_ptr)(asrc + q * 64 + lane),
                                             (las_ptr)(afm_s + q * 256),
                                             16, 0, 0);
        }
    }

    // ---- W-quarter into REGISTERS, issued in the SAME miss round as the
    // DMA (independent; all drained together by barrier #1's vmcnt(0)).
    // wv[e*16+ml] = W[e][g*16+ml][lane]; 80 coalesced 256B wave-loads ----
    float wv[80];
#pragma unroll
    for (int p = 0; p < 80; ++p)
        wv[p] = adj_w[(size_t)(p / 16) * MFD * NFD + (g * 16 + (p % 16)) * NFD + lane];

    // ---- independent small loads, same shadow ----
    const int   bfm_reg = bfm[((size_t)b * NN + i) * NN + lane]; // lane j = type(i,j)
    const int   a_row   = a_bfm[b * NN + i0 + (lane >> 4)];
    const float bv      = bias[g * 16 + (lane & 15)];

    __syncthreads();   // barrier #1: drains DMA + wv + scalars, afm_s ready

    // dependent gather issued NOW: latency hides under phases 2+3,
    // consumed only at the final store.
    const float att = (a_row > 0)
                    ? adj_a[(size_t)(a_row - 1) * MFD + g * 16 + (lane & 15)]
                    : 0.f;

    // ---- phase 2 (1 row/wave): bucket sums, lane = n. Branchless:
    // e wave-uniform (readlane const-idx) -> s_cmp/s_cselect + v_fmac ----
    float ac0 = 0.f, ac1 = 0.f, ac2 = 0.f, ac3 = 0.f, ac4 = 0.f;
#pragma unroll
    for (int j = 0; j < NN; ++j) {
        float v = afm_s[j * NFD + lane];
        int e = __builtin_amdgcn_readlane(bfm_reg, j);
        ac0 = fmaf((e == 1) ? 1.f : 0.f, v, ac0);
        ac1 = fmaf((e == 2) ? 1.f : 0.f, v, ac1);
        ac2 = fmaf((e == 3) ? 1.f : 0.f, v, ac2);
        ac3 = fmaf((e == 4) ? 1.f : 0.f, v, ac3);
        ac4 = fmaf((e == 5) ? 1.f : 0.f, v, ac4);
    }
    ac_s[g][0][lane] = ac0;
    ac_s[g][1][lane] = ac1;
    ac_s[g][2][lane] = ac2;
    ac_s[g][3][lane] = ac3;
    ac_s[g][4][lane] = ac4;

    __syncthreads();   // barrier #2: ac_s ready

    // ---- phase 3: wave g = m-quarter for ALL 4 rows; 20 LDS reads ----
    float acr[4][EFD];
#pragma unroll
    for (int r = 0; r < 4; ++r)
#pragma unroll
        for (int e = 0; e < EFD; ++e)
            acr[r][e] = ac_s[r][e][lane];

    float p[64];   // p[r*16+ml] = partial of (row i0+r, m=g*16+ml) at n=lane
#pragma unroll
    for (int r = 0; r < 4; ++r)
#pragma unroll
        for (int ml = 0; ml < 16; ++ml)
            p[r * 16 + ml] = wv[0 * 16 + ml] * acr[r][0]
                           + wv[1 * 16 + ml] * acr[r][1]
                           + wv[2 * 16 + ml] * acr[r][2]
                           + wv[3 * 16 + ml] * acr[r][3]
                           + wv[4 * 16 + ml] * acr[r][4];

    // ---- verified butterfly transpose-reduce: final lane L = sum_lanes p[L] ----
#pragma unroll
    for (int s = 32; s >= 1; s >>= 1) {
#pragma unroll
        for (int m = 0; m < s; ++m) {
            float lo = p[m], hi = p[m + s];
            bool upper  = (lane & s) != 0;
            float mine  = upper ? hi : lo;
            float other = upper ? lo : hi;
            float recv  = __shfl_xor(other, s, 64);
            p[m] = mine + recv;
        }
    }
    float res = p[0];  // = msg[i0+(lane>>4)][g*16+(lane&15)]

    // ---- epilogue: attention scale + bias ----
    out[((size_t)b * NN + i0 + (lane >> 4)) * MFD + g * 16 + (lane & 15)]
        = res * att + bv;
}

extern "C" void kernel_launch(void* const* d_in, const int* in_sizes, int n_in,
                              void* d_out, int out_size, void* d_ws, size_t ws_size,
                              hipStream_t stream) {
    const float* afm   = (const float*)d_in[0];
    const int*   bfm   = (const int*)d_in[1];
    const int*   a_bfm = (const int*)d_in[2];
    const float* adj_w = (const float*)d_in[3];
    const float* adj_a = (const float*)d_in[4];
    const float* bias  = (const float*)d_in[5];
    float* out = (float*)d_out;

    dim3 grid(256);     // 16 b * 16 rowtiles (4 rows each)
    dim3 block(THREADS);
    ggnn_msgpass_kernel<<<grid, block, 0, stream>>>(afm, bfm, a_bfm, adj_w,
                                                    adj_a, bias, out);
}